// Round 8
// baseline (192.435 us; speedup 1.0000x reference)
//
#include <hip/hip_runtime.h>
#include <stdint.h>

#define N_UNITS   400
#define N_NEIGHB  64
#define C         3
#define S         2
#define T         10      // C + C*S + E, E=1
#define NSLICE    256     // spike slices for the histogram kernel
#define HALF_NB   32      // neighborhoods per half
#define HH        (HALF_NB * N_UNITS)   // 12800 packed ints = 51.2 KB LDS
#define BS        256

// ---------- JAX Threefry-2x32, key = (0, 1) (jax.random.key(1)) ----------
__device__ __forceinline__ uint32_t rotl32(uint32_t x, int d) {
    return (x << d) | (x >> (32 - d));
}

__device__ __forceinline__ void threefry_key01(uint32_t x0, uint32_t x1,
                                               uint32_t& o0, uint32_t& o1) {
    const uint32_t ks0 = 0u;
    const uint32_t ks1 = 1u;
    const uint32_t ks2 = 0x1BD11BDBu;  // 0x1BD11BDA ^ 0 ^ 1
    x0 += ks0; x1 += ks1;
#define TF_RND(r) { x0 += x1; x1 = rotl32(x1, r); x1 ^= x0; }
    TF_RND(13) TF_RND(15) TF_RND(26) TF_RND(6)
    x0 += ks1; x1 += ks2 + 1u;
    TF_RND(17) TF_RND(29) TF_RND(16) TF_RND(24)
    x0 += ks2; x1 += ks0 + 2u;
    TF_RND(13) TF_RND(15) TF_RND(26) TF_RND(6)
    x0 += ks0; x1 += ks1 + 3u;
    TF_RND(17) TF_RND(29) TF_RND(16) TF_RND(24)
    x0 += ks1; x1 += ks2 + 4u;
    TF_RND(13) TF_RND(15) TF_RND(26) TF_RND(6)
    x0 += ks2; x1 += ks0 + 5u;
#undef TF_RND
    o0 = x0; o1 = x1;
}

// jax_threefry_partitionable=True (default since jax 0.4.36):
// bits[i] = x0 ^ x1 of threefry2x32(key, (i >> 32, i & 0xffffffff)).
__device__ __forceinline__ int explore_index(int i, int ne) {
    uint32_t o0, o1;
    threefry_key01(0u, (uint32_t)i, o0, o1);
    uint32_t bits = o0 ^ o1;
    float u = __uint_as_float((bits >> 9) | 0x3F800000u) - 1.0f;
    int t = (int)floorf(u * (float)ne);
    return min(t, ne - 1);
}

// ---------- kA: packed top-column partial histograms ----------------------
// One 32-bit word per (nb,u): lo16 = top0 count (H0), hi16 = top1+top2 (H12).
// grid = NSLICE*2; block g: half h = g&1, slice s = g>>1. 3 LDS atomics/spike.
__global__ void k_histA(const int* __restrict__ top,
                        const int* __restrict__ nbid,
                        uint32_t* __restrict__ PA, int n, int chunk) {
    __shared__ uint32_t hist[HH];
    for (int k = threadIdx.x; k < HH; k += blockDim.x) hist[k] = 0u;
    __syncthreads();
    int h = blockIdx.x & 1, s = blockIdx.x >> 1;
    int lo = s * chunk, hi = min(n, lo + chunk);
    const int4* top4 = (const int4*)top;
#define PROC(nb, t0, t1, t2) if (((nb) >> 5) == h) { \
    int r = ((nb) & 31) * N_UNITS; \
    atomicAdd(&hist[r + (t0)], 1u); \
    atomicAdd(&hist[r + (t1)], 0x10000u); \
    atomicAdd(&hist[r + (t2)], 0x10000u); }
    for (int i0 = lo + threadIdx.x * 4; i0 < hi; i0 += blockDim.x * 4) {
        if (i0 + 4 <= hi) {
            int4 nb4 = *(const int4*)(nbid + i0);
            int j = (i0 * 3) >> 2;
            int4 ta = top4[j], tb = top4[j + 1], tc = top4[j + 2];
            PROC(nb4.x, ta.x, ta.y, ta.z)
            PROC(nb4.y, ta.w, tb.x, tb.y)
            PROC(nb4.z, tb.z, tb.w, tc.x)
            PROC(nb4.w, tc.y, tc.z, tc.w)
        } else {
            for (int i = i0; i < hi; ++i)
                PROC(nbid[i], top[3 * i], top[3 * i + 1], top[3 * i + 2])
        }
    }
#undef PROC
    __syncthreads();
    uint32_t* Pb = PA + (size_t)blockIdx.x * HH;
    for (int k = threadIdx.x; k < HH; k += blockDim.x) Pb[k] = hist[k];
}

// ---------- kB: fused reduce + tables + base counts -----------------------
__global__ void k_tables_base(const uint32_t* __restrict__ PA,
                              const int* __restrict__ usn,
                              int* __restrict__ wtbl,
                              int* __restrict__ wne,
                              float* __restrict__ out_counts) {
    __shared__ int scan[512];
    __shared__ int s_c[N_UNITS];
    __shared__ int s_h3[N_UNITS];
    int b = blockIdx.x, u = threadIdx.x;
    int h = b >> 5;
    int base = (b & 31) * N_UNITS;
    int h0 = 0, h12 = 0;
    if (u < N_UNITS) {
        for (int s = 0; s < NSLICE; ++s) {
            uint32_t w = PA[(size_t)(s * 2 + h) * HH + base + u];
            h0  += (int)(w & 0xFFFFu);
            h12 += (int)(w >> 16);
        }
        int h3 = h0 + h12;
        s_h3[u] = h3;
        s_c[u] = h3;              // top0 + top1/top2 contributions
    }
    int p = (u < N_UNITS && h0 > 0) ? 1 : 0;
    scan[u] = p;
    __syncthreads();
    for (int off = 1; off < 512; off <<= 1) {
        int add = (u >= off) ? scan[u - off] : 0;
        __syncthreads();
        scan[u] += add;
        __syncthreads();
    }
    if (p) wtbl[b * N_UNITS + scan[u] - 1] = u;
    if (u == 511) wne[b] = scan[511];
    if (u < N_UNITS) {
        int h3 = s_h3[u];
        if (h3 > 0) {
            int2 nbr = ((const int2*)usn)[u];
            atomicAdd(&s_c[nbr.x], h3);
            atomicAdd(&s_c[nbr.y], h3);
        }
    }
    __syncthreads();
    if (u < N_UNITS)
        out_counts[u * N_NEIGHB + b] = (float)s_c[u];
}

// ---------- k_main: candidates + scores, LDS-staged coalesced stores ------
__global__ void k_main(const float* __restrict__ logliks,
                       const int* __restrict__ top,
                       const int* __restrict__ usn,
                       const int* __restrict__ nbid,
                       const int* __restrict__ wtbl,
                       const int* __restrict__ wne,
                       float* __restrict__ out_counts,
                       float* __restrict__ out_cand,
                       float* __restrict__ out_scores,
                       int n) {
    __shared__ int   s_usn[N_UNITS * S];
    __shared__ float s_ll[N_UNITS];
    __shared__ int   s_ne[N_NEIGHB];
    __shared__ int   s_top[BS * 3];
    __shared__ float s_bc[BS * T];   // cand staging
    __shared__ float s_bs[BS * T];   // score staging
    int tid = threadIdx.x;
    int base = blockIdx.x * BS;
    int cnt = min(BS, n - base);     // active spikes in this block

    for (int k = tid; k < N_UNITS * S; k += BS) s_usn[k] = usn[k];
    for (int k = tid; k < N_UNITS; k += BS)     s_ll[k]  = logliks[k];
    for (int k = tid; k < N_NEIGHB; k += BS)    s_ne[k]  = wne[k];
    // stage this block's top rows via int4 (cnt*3 ints)
    if (cnt == BS) {
        if (tid < (BS * 3) / 4)
            ((int4*)s_top)[tid] = ((const int4*)(top + (size_t)base * 3))[tid];
    } else {
        for (int k = tid; k < cnt * 3; k += BS) s_top[k] = top[(size_t)base * 3 + k];
    }
    __syncthreads();

    int i = base + tid;
    if (i < n) {
        int nb = nbid[i];
        int cand[T];
        cand[0] = s_top[tid * 3 + 0];
        cand[1] = s_top[tid * 3 + 1];
        cand[2] = s_top[tid * 3 + 2];
#pragma unroll
        for (int c = 0; c < C; ++c) {
            cand[C + 2 * c]     = s_usn[cand[c] * 2 + 0];
            cand[C + 2 * c + 1] = s_usn[cand[c] * 2 + 1];
        }
        int ne = s_ne[nb];
        if (ne > 0) {
            int t = explore_index(i, ne);
            int ex = wtbl[nb * N_UNITS + t];
            cand[T - 1] = ex;
            // explore tail-add (pre-dup): finishes base counts
            atomicAdd(&out_counts[ex * N_NEIGHB + nb], 1.0f);
        } else {
            cand[T - 1] = -1;
        }
#pragma unroll
        for (int jj = 0; jj < T; ++jj) {
            bool dup = false;
#pragma unroll
            for (int k = 0; k < jj; ++k) dup |= (cand[k] == cand[jj]);
            int v = dup ? -1 : cand[jj];   // reference erases dups to -1
            s_bc[tid * T + jj] = (float)v;
            s_bs[tid * T + jj] = (v >= 0) ? s_ll[v] : 0.0f;
        }
    }
    __syncthreads();

    // dense coalesced dump: cnt*T floats per array, float4 vectorized
    int nfloat = cnt * T;
    float* oc = out_cand   + (size_t)base * T;
    float* os = out_scores + (size_t)base * T;
    int nvec = nfloat & ~3;
    for (int e = tid * 4; e < nvec; e += BS * 4) {
        *(float4*)(oc + e) = *(const float4*)(s_bc + e);
        *(float4*)(os + e) = *(const float4*)(s_bs + e);
    }
    for (int e = nvec + tid; e < nfloat; e += BS) {
        oc[e] = s_bc[e];
        os[e] = s_bs[e];
    }
}

extern "C" void kernel_launch(void* const* d_in, const int* in_sizes, int n_in,
                              void* d_out, int out_size, void* d_ws, size_t ws_size,
                              hipStream_t stream) {
    const float* logliks = (const float*)d_in[0];
    const int*   top     = (const int*)d_in[1];
    const int*   usn     = (const int*)d_in[2];
    const int*   nbid    = (const int*)d_in[3];

    int n = in_sizes[3];                              // N_SPIKES
    int chunk = ((n + NSLICE - 1) / NSLICE + 3) & ~3; // 4-aligned slice length

    float* out        = (float*)d_out;
    float* out_cand   = out;
    float* out_counts = out + (size_t)n * T;
    float* out_scores = out_counts + (size_t)N_UNITS * N_NEIGHB;

    // PA partials live in the scores region of d_out (512*12800*4 = 26.2 MB
    // < 40 MB); fully consumed by k_tables_base before k_main overwrites.
    uint32_t* PA = (uint32_t*)out_scores;

    // Workspace: explore tables only (~103 KB, plain stores).
    int* wtbl = (int*)d_ws;                 // [64][400]
    int* wne  = wtbl + N_NEIGHB * N_UNITS;  // [64]

    k_histA      <<<NSLICE * 2, BS, 0, stream>>>(top, nbid, PA, n, chunk);
    k_tables_base<<<N_NEIGHB, 512, 0, stream>>>(PA, usn, wtbl, wne, out_counts);
    k_main       <<<(n + BS - 1) / BS, BS, 0, stream>>>(logliks, top, usn, nbid,
                                                        wtbl, wne, out_counts,
                                                        out_cand, out_scores, n);
}

// Round 9
// 164.840 us; speedup vs baseline: 1.1674x; 1.1674x over previous
//
#include <hip/hip_runtime.h>
#include <stdint.h>

#define N_UNITS   400
#define N_NEIGHB  64
#define C         3
#define S         2
#define T         10      // C + C*S + E, E=1
#define NSLICE_A  128     // spike slices, top-hist kernel
#define NSLICE_E  256     // spike slices, explore-hist kernel
#define HALF_NB   32      // neighborhoods per half (kA)
#define HH        (HALF_NB * N_UNITS)   // 12800 packed ints = 51.2 KB LDS
#define EH        (N_UNITS * 32)        // 12800 words: 64 nb 16-bit-packed
#define BS        256

// ---------- JAX Threefry-2x32, key = (0, 1) (jax.random.key(1)) ----------
__device__ __forceinline__ uint32_t rotl32(uint32_t x, int d) {
    return (x << d) | (x >> (32 - d));
}

__device__ __forceinline__ void threefry_key01(uint32_t x0, uint32_t x1,
                                               uint32_t& o0, uint32_t& o1) {
    const uint32_t ks0 = 0u;
    const uint32_t ks1 = 1u;
    const uint32_t ks2 = 0x1BD11BDBu;  // 0x1BD11BDA ^ 0 ^ 1
    x0 += ks0; x1 += ks1;
#define TF_RND(r) { x0 += x1; x1 = rotl32(x1, r); x1 ^= x0; }
    TF_RND(13) TF_RND(15) TF_RND(26) TF_RND(6)
    x0 += ks1; x1 += ks2 + 1u;
    TF_RND(17) TF_RND(29) TF_RND(16) TF_RND(24)
    x0 += ks2; x1 += ks0 + 2u;
    TF_RND(13) TF_RND(15) TF_RND(26) TF_RND(6)
    x0 += ks0; x1 += ks1 + 3u;
    TF_RND(17) TF_RND(29) TF_RND(16) TF_RND(24)
    x0 += ks1; x1 += ks2 + 4u;
    TF_RND(13) TF_RND(15) TF_RND(26) TF_RND(6)
    x0 += ks2; x1 += ks0 + 5u;
#undef TF_RND
    o0 = x0; o1 = x1;
}

// jax_threefry_partitionable=True (default since jax 0.4.36):
// bits[i] = x0 ^ x1 of threefry2x32(key, (i >> 32, i & 0xffffffff)).
__device__ __forceinline__ int explore_index(int i, int ne) {
    uint32_t o0, o1;
    threefry_key01(0u, (uint32_t)i, o0, o1);
    uint32_t bits = o0 ^ o1;
    float u = __uint_as_float((bits >> 9) | 0x3F800000u) - 1.0f;
    int t = (int)floorf(u * (float)ne);
    return min(t, ne - 1);
}

// ---------- kA: packed top-column partial histograms ----------------------
// One 32-bit word per (nb,u): lo16 = top0 count (H0), hi16 = top1+top2 (H12).
// grid = NSLICE_A*2; block g: half h = g&1, slice s = g>>1. 3 LDS atomics/spike.
__global__ void k_histA(const int* __restrict__ top,
                        const int* __restrict__ nbid,
                        uint32_t* __restrict__ PA, int n, int chunk) {
    __shared__ uint32_t hist[HH];
    for (int k = threadIdx.x; k < HH; k += blockDim.x) hist[k] = 0u;
    __syncthreads();
    int h = blockIdx.x & 1, s = blockIdx.x >> 1;
    int lo = s * chunk, hi = min(n, lo + chunk);
    const int4* top4 = (const int4*)top;
#define PROC(nb, t0, t1, t2) if (((nb) >> 5) == h) { \
    int r = ((nb) & 31) * N_UNITS; \
    atomicAdd(&hist[r + (t0)], 1u); \
    atomicAdd(&hist[r + (t1)], 0x10000u); \
    atomicAdd(&hist[r + (t2)], 0x10000u); }
    for (int i0 = lo + threadIdx.x * 4; i0 < hi; i0 += blockDim.x * 4) {
        if (i0 + 4 <= hi) {
            int4 nb4 = *(const int4*)(nbid + i0);
            int j = (i0 * 3) >> 2;
            int4 ta = top4[j], tb = top4[j + 1], tc = top4[j + 2];
            PROC(nb4.x, ta.x, ta.y, ta.z)
            PROC(nb4.y, ta.w, tb.x, tb.y)
            PROC(nb4.z, tb.z, tb.w, tc.x)
            PROC(nb4.w, tc.y, tc.z, tc.w)
        } else {
            for (int i = i0; i < hi; ++i)
                PROC(nbid[i], top[3 * i], top[3 * i + 1], top[3 * i + 2])
        }
    }
#undef PROC
    __syncthreads();
    uint32_t* Pb = PA + (size_t)blockIdx.x * HH;
    for (int k = threadIdx.x; k < HH; k += blockDim.x) Pb[k] = hist[k];
}

// ---------- kB: fused reduce + tables + base counts -----------------------
// Base counts = H0 + H12 + search-expansion; explore added later by k_finalE.
__global__ void k_tables_base(const uint32_t* __restrict__ PA,
                              const int* __restrict__ usn,
                              int* __restrict__ wtbl,
                              int* __restrict__ wne,
                              float* __restrict__ out_counts) {
    __shared__ int scan[512];
    __shared__ int s_c[N_UNITS];
    __shared__ int s_h3[N_UNITS];
    int b = blockIdx.x, u = threadIdx.x;
    int h = b >> 5;
    int base = (b & 31) * N_UNITS;
    int h0 = 0, h12 = 0;
    if (u < N_UNITS) {
        for (int s = 0; s < NSLICE_A; ++s) {
            uint32_t w = PA[(size_t)(s * 2 + h) * HH + base + u];
            h0  += (int)(w & 0xFFFFu);
            h12 += (int)(w >> 16);
        }
        int h3 = h0 + h12;
        s_h3[u] = h3;
        s_c[u] = h3;              // top0 + top1/top2 contributions
    }
    int p = (u < N_UNITS && h0 > 0) ? 1 : 0;
    scan[u] = p;
    __syncthreads();
    for (int off = 1; off < 512; off <<= 1) {
        int add = (u >= off) ? scan[u - off] : 0;
        __syncthreads();
        scan[u] += add;
        __syncthreads();
    }
    if (p) wtbl[b * N_UNITS + scan[u] - 1] = u;
    if (u == 511) wne[b] = scan[511];
    if (u < N_UNITS) {
        int h3 = s_h3[u];
        if (h3 > 0) {
            int2 nbr = ((const int2*)usn)[u];
            atomicAdd(&s_c[nbr.x], h3);
            atomicAdd(&s_c[nbr.y], h3);
        }
    }
    __syncthreads();
    if (u < N_UNITS)
        out_counts[u * N_NEIGHB + b] = (float)s_c[u];
}

// ---------- kE: explore-column partial histograms (LDS only) --------------
// 16-bit packed: word u*32 + (nb>>1), halfword nb&1. 1 LDS atomic/spike.
__global__ void k_histE(const int* __restrict__ nbid,
                        const int* __restrict__ wtbl,
                        const int* __restrict__ wne,
                        uint32_t* __restrict__ PD, int n, int chunk) {
    __shared__ uint32_t hist[EH];
    __shared__ int s_ne[N_NEIGHB];
    for (int k = threadIdx.x; k < EH; k += blockDim.x) hist[k] = 0u;
    for (int k = threadIdx.x; k < N_NEIGHB; k += blockDim.x) s_ne[k] = wne[k];
    __syncthreads();
    int lo = blockIdx.x * chunk, hi = min(n, lo + chunk);
#define PROCE(i, nb) { int ne = s_ne[nb]; \
    if (ne > 0) { int t = explore_index((i), ne); \
        int ex = wtbl[(nb) * N_UNITS + t]; \
        atomicAdd(&hist[ex * 32 + ((nb) >> 1)], ((nb) & 1) ? 0x10000u : 1u); } }
    for (int i0 = lo + threadIdx.x * 4; i0 < hi; i0 += blockDim.x * 4) {
        if (i0 + 4 <= hi) {
            int4 nb4 = *(const int4*)(nbid + i0);
            PROCE(i0 + 0, nb4.x)
            PROCE(i0 + 1, nb4.y)
            PROCE(i0 + 2, nb4.z)
            PROCE(i0 + 3, nb4.w)
        } else {
            for (int i = i0; i < hi; ++i) PROCE(i, nbid[i])
        }
    }
#undef PROCE
    __syncthreads();
    uint32_t* Pb = PD + (size_t)blockIdx.x * EH;
    for (int k = threadIdx.x; k < EH; k += blockDim.x) Pb[k] = hist[k];
}

// ---------- kF: reduce explore partials into out_counts -------------------
__global__ void k_finalE(const uint32_t* __restrict__ PD,
                         float* __restrict__ out_counts) {
    int c = blockIdx.x * blockDim.x + threadIdx.x;   // c = u*64 + nb
    if (c >= N_UNITS * N_NEIGHB) return;
    int u = c >> 6, nb = c & 63;
    int w = u * 32 + (nb >> 1), sh = (nb & 1) * 16;
    int sum = 0;
    for (int s = 0; s < NSLICE_E; ++s)
        sum += (int)((PD[(size_t)s * EH + w] >> sh) & 0xFFFFu);
    out_counts[c] += (float)sum;
}

// ---------- k_main: candidates + scores (no atomics) ----------------------
__global__ void k_main(const float* __restrict__ logliks,
                       const int* __restrict__ top,
                       const int* __restrict__ usn,
                       const int* __restrict__ nbid,
                       const int* __restrict__ wtbl,
                       const int* __restrict__ wne,
                       float* __restrict__ out_cand,
                       float* __restrict__ out_scores,
                       int n) {
    __shared__ int   s_usn[N_UNITS * S];
    __shared__ float s_ll[N_UNITS];
    __shared__ int   s_ne[N_NEIGHB];
    __shared__ int   s_top[BS * 3];
    __shared__ float s_bc[BS * T];   // cand staging
    __shared__ float s_bs[BS * T];   // score staging
    int tid = threadIdx.x;
    int base = blockIdx.x * BS;
    int cnt = min(BS, n - base);

    for (int k = tid; k < N_UNITS * S; k += BS) s_usn[k] = usn[k];
    for (int k = tid; k < N_UNITS; k += BS)     s_ll[k]  = logliks[k];
    for (int k = tid; k < N_NEIGHB; k += BS)    s_ne[k]  = wne[k];
    if (cnt == BS) {
        if (tid < (BS * 3) / 4)
            ((int4*)s_top)[tid] = ((const int4*)(top + (size_t)base * 3))[tid];
    } else {
        for (int k = tid; k < cnt * 3; k += BS) s_top[k] = top[(size_t)base * 3 + k];
    }
    __syncthreads();

    int i = base + tid;
    if (i < n) {
        int nb = nbid[i];
        int cand[T];
        cand[0] = s_top[tid * 3 + 0];
        cand[1] = s_top[tid * 3 + 1];
        cand[2] = s_top[tid * 3 + 2];
#pragma unroll
        for (int c = 0; c < C; ++c) {
            cand[C + 2 * c]     = s_usn[cand[c] * 2 + 0];
            cand[C + 2 * c + 1] = s_usn[cand[c] * 2 + 1];
        }
        int ne = s_ne[nb];
        if (ne > 0) {
            int t = explore_index(i, ne);
            cand[T - 1] = wtbl[nb * N_UNITS + t];
        } else {
            cand[T - 1] = -1;
        }
#pragma unroll
        for (int jj = 0; jj < T; ++jj) {
            bool dup = false;
#pragma unroll
            for (int k = 0; k < jj; ++k) dup |= (cand[k] == cand[jj]);
            int v = dup ? -1 : cand[jj];   // reference erases dups to -1
            s_bc[tid * T + jj] = (float)v;
            s_bs[tid * T + jj] = (v >= 0) ? s_ll[v] : 0.0f;
        }
    }
    __syncthreads();

    int nfloat = cnt * T;
    float* oc = out_cand   + (size_t)base * T;
    float* os = out_scores + (size_t)base * T;
    int nvec = nfloat & ~3;
    for (int e = tid * 4; e < nvec; e += BS * 4) {
        *(float4*)(oc + e) = *(const float4*)(s_bc + e);
        *(float4*)(os + e) = *(const float4*)(s_bs + e);
    }
    for (int e = nvec + tid; e < nfloat; e += BS) {
        oc[e] = s_bc[e];
        os[e] = s_bs[e];
    }
}

extern "C" void kernel_launch(void* const* d_in, const int* in_sizes, int n_in,
                              void* d_out, int out_size, void* d_ws, size_t ws_size,
                              hipStream_t stream) {
    const float* logliks = (const float*)d_in[0];
    const int*   top     = (const int*)d_in[1];
    const int*   usn     = (const int*)d_in[2];
    const int*   nbid    = (const int*)d_in[3];

    int n = in_sizes[3];                                 // N_SPIKES
    int chunkA = ((n + NSLICE_A - 1) / NSLICE_A + 3) & ~3;
    int chunkE = ((n + NSLICE_E - 1) / NSLICE_E + 3) & ~3;

    float* out        = (float*)d_out;
    float* out_cand   = out;
    float* out_counts = out + (size_t)n * T;
    float* out_scores = out_counts + (size_t)N_UNITS * N_NEIGHB;

    // Scratch lives in the scores region of d_out (40 MB), consumed strictly
    // before k_main overwrites it:
    //   PA: 256 blocks * 12800 * 4B = 13.1 MB  (dead after k_tables_base)
    //   PD: 256 blocks * 12800 * 4B = 13.1 MB  (same offset, dead after k_finalE)
    uint32_t* PA = (uint32_t*)out_scores;
    uint32_t* PD = (uint32_t*)out_scores;

    // Workspace: explore tables only (~103 KB, plain stores).
    int* wtbl = (int*)d_ws;                 // [64][400]
    int* wne  = wtbl + N_NEIGHB * N_UNITS;  // [64]

    int m = N_UNITS * N_NEIGHB;
    k_histA      <<<NSLICE_A * 2, BS, 0, stream>>>(top, nbid, PA, n, chunkA);
    k_tables_base<<<N_NEIGHB, 512, 0, stream>>>(PA, usn, wtbl, wne, out_counts);
    k_histE      <<<NSLICE_E, BS, 0, stream>>>(nbid, wtbl, wne, PD, n, chunkE);
    k_finalE     <<<(m + BS - 1) / BS, BS, 0, stream>>>(PD, out_counts);
    k_main       <<<(n + BS - 1) / BS, BS, 0, stream>>>(logliks, top, usn, nbid,
                                                        wtbl, wne,
                                                        out_cand, out_scores, n);
}

// Round 10
// 144.894 us; speedup vs baseline: 1.3281x; 1.1377x over previous
//
#include <hip/hip_runtime.h>
#include <stdint.h>

#define N_UNITS   400
#define N_NEIGHB  64
#define C         3
#define S         2
#define T         10      // C + C*S + E, E=1
#define NSLICE_A  128     // spike slices, top-hist kernel
#define HALF_NB   32      // neighborhoods per half (kA)
#define HH        (HALF_NB * N_UNITS)   // 12800 packed ints = 51.2 KB LDS
#define EH        (N_UNITS * 32)        // 12800 words: 64 nb 16-bit packed
#define BS        256
#define MB        512     // k_main blocks (explore-hist partial count)

// ---------- JAX Threefry-2x32, key = (0, 1) (jax.random.key(1)) ----------
__device__ __forceinline__ uint32_t rotl32(uint32_t x, int d) {
    return (x << d) | (x >> (32 - d));
}

__device__ __forceinline__ void threefry_key01(uint32_t x0, uint32_t x1,
                                               uint32_t& o0, uint32_t& o1) {
    const uint32_t ks0 = 0u;
    const uint32_t ks1 = 1u;
    const uint32_t ks2 = 0x1BD11BDBu;  // 0x1BD11BDA ^ 0 ^ 1
    x0 += ks0; x1 += ks1;
#define TF_RND(r) { x0 += x1; x1 = rotl32(x1, r); x1 ^= x0; }
    TF_RND(13) TF_RND(15) TF_RND(26) TF_RND(6)
    x0 += ks1; x1 += ks2 + 1u;
    TF_RND(17) TF_RND(29) TF_RND(16) TF_RND(24)
    x0 += ks2; x1 += ks0 + 2u;
    TF_RND(13) TF_RND(15) TF_RND(26) TF_RND(6)
    x0 += ks0; x1 += ks1 + 3u;
    TF_RND(17) TF_RND(29) TF_RND(16) TF_RND(24)
    x0 += ks1; x1 += ks2 + 4u;
    TF_RND(13) TF_RND(15) TF_RND(26) TF_RND(6)
    x0 += ks2; x1 += ks0 + 5u;
#undef TF_RND
    o0 = x0; o1 = x1;
}

// jax_threefry_partitionable=True (default since jax 0.4.36):
// bits[i] = x0 ^ x1 of threefry2x32(key, (i >> 32, i & 0xffffffff)).
__device__ __forceinline__ int explore_index(int i, int ne) {
    uint32_t o0, o1;
    threefry_key01(0u, (uint32_t)i, o0, o1);
    uint32_t bits = o0 ^ o1;
    float u = __uint_as_float((bits >> 9) | 0x3F800000u) - 1.0f;
    int t = (int)floorf(u * (float)ne);
    return min(t, ne - 1);
}

// ---------- kA: packed top-column partial histograms ----------------------
// One 32-bit word per (nb,u): lo16 = top0 count (H0), hi16 = top1+top2 (H12).
// grid = NSLICE_A*2; block g: half h = g&1, slice s = g>>1. 3 LDS atomics/spike.
__global__ void k_histA(const int* __restrict__ top,
                        const int* __restrict__ nbid,
                        uint32_t* __restrict__ PA, int n, int chunk) {
    __shared__ uint32_t hist[HH];
    for (int k = threadIdx.x; k < HH; k += blockDim.x) hist[k] = 0u;
    __syncthreads();
    int h = blockIdx.x & 1, s = blockIdx.x >> 1;
    int lo = s * chunk, hi = min(n, lo + chunk);
    const int4* top4 = (const int4*)top;
#define PROC(nb, t0, t1, t2) if (((nb) >> 5) == h) { \
    int r = ((nb) & 31) * N_UNITS; \
    atomicAdd(&hist[r + (t0)], 1u); \
    atomicAdd(&hist[r + (t1)], 0x10000u); \
    atomicAdd(&hist[r + (t2)], 0x10000u); }
    for (int i0 = lo + threadIdx.x * 4; i0 < hi; i0 += blockDim.x * 4) {
        if (i0 + 4 <= hi) {
            int4 nb4 = *(const int4*)(nbid + i0);
            int j = (i0 * 3) >> 2;
            int4 ta = top4[j], tb = top4[j + 1], tc = top4[j + 2];
            PROC(nb4.x, ta.x, ta.y, ta.z)
            PROC(nb4.y, ta.w, tb.x, tb.y)
            PROC(nb4.z, tb.z, tb.w, tc.x)
            PROC(nb4.w, tc.y, tc.z, tc.w)
        } else {
            for (int i = i0; i < hi; ++i)
                PROC(nbid[i], top[3 * i], top[3 * i + 1], top[3 * i + 2])
        }
    }
#undef PROC
    __syncthreads();
    uint32_t* Pb = PA + (size_t)blockIdx.x * HH;
    for (int k = threadIdx.x; k < HH; k += blockDim.x) Pb[k] = hist[k];
}

// ---------- kB: fused reduce + tables + base counts -----------------------
// Base counts = H0 + H12 + search-expansion; explore added later by k_finalE.
__global__ void k_tables_base(const uint32_t* __restrict__ PA,
                              const int* __restrict__ usn,
                              int* __restrict__ wtbl,
                              int* __restrict__ wne,
                              float* __restrict__ out_counts) {
    __shared__ int scan[512];
    __shared__ int s_c[N_UNITS];
    __shared__ int s_h3[N_UNITS];
    int b = blockIdx.x, u = threadIdx.x;
    int h = b >> 5;
    int base = (b & 31) * N_UNITS;
    int h0 = 0, h12 = 0;
    if (u < N_UNITS) {
#pragma unroll 8
        for (int s = 0; s < NSLICE_A; ++s) {
            uint32_t w = PA[(size_t)(s * 2 + h) * HH + base + u];
            h0  += (int)(w & 0xFFFFu);
            h12 += (int)(w >> 16);
        }
        int h3 = h0 + h12;
        s_h3[u] = h3;
        s_c[u] = h3;              // top0 + top1/top2 contributions
    }
    int p = (u < N_UNITS && h0 > 0) ? 1 : 0;
    scan[u] = p;
    __syncthreads();
    for (int off = 1; off < 512; off <<= 1) {
        int add = (u >= off) ? scan[u - off] : 0;
        __syncthreads();
        scan[u] += add;
        __syncthreads();
    }
    if (p) wtbl[b * N_UNITS + scan[u] - 1] = u;
    if (u == 511) wne[b] = scan[511];
    if (u < N_UNITS) {
        int h3 = s_h3[u];
        if (h3 > 0) {
            int2 nbr = ((const int2*)usn)[u];
            atomicAdd(&s_c[nbr.x], h3);
            atomicAdd(&s_c[nbr.y], h3);
        }
    }
    __syncthreads();
    if (u < N_UNITS)
        out_counts[u * N_NEIGHB + b] = (float)s_c[u];
}

// ---------- k_main: candidates + scores + explore LDS histogram -----------
// grid = MB blocks; block handles chunk consecutive spikes. 16-bit-packed
// explore hist (word u*32 + nb/2); per-block partial dumped to PD.
__global__ void k_main(const float* __restrict__ logliks,
                       const int* __restrict__ top,
                       const int* __restrict__ usn,
                       const int* __restrict__ nbid,
                       const int* __restrict__ wtbl,
                       const int* __restrict__ wne,
                       uint32_t* __restrict__ PD,
                       float* __restrict__ out_cand,
                       float* __restrict__ out_scores,
                       int n, int chunk) {
    __shared__ uint32_t hist[EH];
    __shared__ int   s_usn[N_UNITS * S];
    __shared__ float s_ll[N_UNITS];
    __shared__ int   s_ne[N_NEIGHB];
    int tid = threadIdx.x;
    for (int k = tid; k < EH; k += BS) hist[k] = 0u;
    for (int k = tid; k < N_UNITS * S; k += BS) s_usn[k] = usn[k];
    for (int k = tid; k < N_UNITS; k += BS)     s_ll[k]  = logliks[k];
    for (int k = tid; k < N_NEIGHB; k += BS)    s_ne[k]  = wne[k];
    __syncthreads();

    int lo = blockIdx.x * chunk, hi = min(n, lo + chunk);
    for (int i = lo + tid; i < hi; i += BS) {
        int nb = nbid[i];
        int cand[T];
        cand[0] = top[i * 3 + 0];
        cand[1] = top[i * 3 + 1];
        cand[2] = top[i * 3 + 2];
#pragma unroll
        for (int c = 0; c < C; ++c) {
            cand[C + 2 * c]     = s_usn[cand[c] * 2 + 0];
            cand[C + 2 * c + 1] = s_usn[cand[c] * 2 + 1];
        }
        int ne = s_ne[nb];
        if (ne > 0) {
            int t = explore_index(i, ne);
            int ex = wtbl[nb * N_UNITS + t];
            cand[T - 1] = ex;
            // explore tail-count (pre-dup), LDS only
            atomicAdd(&hist[ex * 32 + (nb >> 1)], (nb & 1) ? 0x10000u : 1u);
        } else {
            cand[T - 1] = -1;
        }

        float vc[T], vs[T];
#pragma unroll
        for (int jj = 0; jj < T; ++jj) {
            bool dup = false;
#pragma unroll
            for (int k = 0; k < jj; ++k) dup |= (cand[k] == cand[jj]);
            int v = dup ? -1 : cand[jj];   // reference erases dups to -1
            vc[jj] = (float)v;
            vs[jj] = (v >= 0) ? s_ll[v] : 0.0f;
        }
        float2* oc2 = (float2*)(out_cand   + (size_t)i * T);
        float2* os2 = (float2*)(out_scores + (size_t)i * T);
#pragma unroll
        for (int jj = 0; jj < T / 2; ++jj) {
            oc2[jj] = make_float2(vc[2 * jj], vc[2 * jj + 1]);
            os2[jj] = make_float2(vs[2 * jj], vs[2 * jj + 1]);
        }
    }
    __syncthreads();
    uint32_t* Pb = PD + (size_t)blockIdx.x * EH;
    for (int k = tid; k < EH; k += BS) Pb[k] = hist[k];
}

// ---------- kF: parallel reduce explore partials into out_counts ----------
// grid = EH/64 = 200 blocks x 256. Thread (w_local = tid&63, g = tid>>2/..):
// sums its quarter of the MB slices for word w; LDS combine; g==0 writes
// both packed neighborhoods as one float2.
__global__ void k_finalE(const uint32_t* __restrict__ PD,
                         float* __restrict__ out_counts) {
    __shared__ uint32_t red[256];
    int tid = threadIdx.x;
    int wl = tid & 63, g = tid >> 6;            // 4 slice groups
    int w = blockIdx.x * 64 + wl;               // word index in [0, EH)
    uint32_t sum = 0;
#pragma unroll 8
    for (int s = g * (MB / 4); s < (g + 1) * (MB / 4); ++s)
        sum += PD[(size_t)s * EH + w];
    red[tid] = sum;
    __syncthreads();
    if (g == 0) {
        uint32_t tot = red[wl] + red[wl + 64] + red[wl + 128] + red[wl + 192];
        int u = w >> 5, nb2 = (w & 31) * 2;     // packed pair (nb2, nb2+1)
        float2* p = (float2*)(out_counts + u * N_NEIGHB + nb2);
        float2 v = *p;
        v.x += (float)(tot & 0xFFFFu);
        v.y += (float)(tot >> 16);
        *p = v;
    }
}

extern "C" void kernel_launch(void* const* d_in, const int* in_sizes, int n_in,
                              void* d_out, int out_size, void* d_ws, size_t ws_size,
                              hipStream_t stream) {
    const float* logliks = (const float*)d_in[0];
    const int*   top     = (const int*)d_in[1];
    const int*   usn     = (const int*)d_in[2];
    const int*   nbid    = (const int*)d_in[3];

    int n = in_sizes[3];                                 // N_SPIKES
    int chunkA = ((n + NSLICE_A - 1) / NSLICE_A + 3) & ~3;
    int chunkM = (n + MB - 1) / MB;

    float* out        = (float*)d_out;
    float* out_cand   = out;
    float* out_counts = out + (size_t)n * T;
    float* out_scores = out_counts + (size_t)N_UNITS * N_NEIGHB;

    // All scratch in d_ws (~240 MB available; we use ~39.5 MB):
    int*      wtbl = (int*)d_ws;                         // [64][400]
    int*      wne  = wtbl + N_NEIGHB * N_UNITS;          // [64]
    uint32_t* PA   = (uint32_t*)(wne + 64);              // 256*12800 = 13.1 MB
    uint32_t* PD   = PA + (size_t)NSLICE_A * 2 * HH;     // 512*12800 = 26.2 MB

    k_histA      <<<NSLICE_A * 2, BS, 0, stream>>>(top, nbid, PA, n, chunkA);
    k_tables_base<<<N_NEIGHB, 512, 0, stream>>>(PA, usn, wtbl, wne, out_counts);
    k_main       <<<MB, BS, 0, stream>>>(logliks, top, usn, nbid, wtbl, wne,
                                         PD, out_cand, out_scores, n, chunkM);
    k_finalE     <<<EH / 64, BS, 0, stream>>>(PD, out_counts);
}

// Round 11
// 143.823 us; speedup vs baseline: 1.3380x; 1.0074x over previous
//
#include <hip/hip_runtime.h>
#include <stdint.h>

#define N_UNITS   400
#define N_NEIGHB  64
#define C         3
#define S         2
#define T         10      // C + C*S + E, E=1
#define NSLICE_A  128     // spike slices, top-hist kernel
#define HALF_NB   32      // neighborhoods per half (kA)
#define HH        (HALF_NB * N_UNITS)   // 12800 packed ints = 51.2 KB LDS
#define EH        (N_UNITS * 32)        // 12800 words: 64 nb 16-bit packed
#define BS        256
#define MB        512     // k_main blocks (explore-hist partial count)

// ---------- JAX Threefry-2x32, key = (0, 1) (jax.random.key(1)) ----------
__device__ __forceinline__ uint32_t rotl32(uint32_t x, int d) {
    return (x << d) | (x >> (32 - d));
}

__device__ __forceinline__ void threefry_key01(uint32_t x0, uint32_t x1,
                                               uint32_t& o0, uint32_t& o1) {
    const uint32_t ks0 = 0u;
    const uint32_t ks1 = 1u;
    const uint32_t ks2 = 0x1BD11BDBu;  // 0x1BD11BDA ^ 0 ^ 1
    x0 += ks0; x1 += ks1;
#define TF_RND(r) { x0 += x1; x1 = rotl32(x1, r); x1 ^= x0; }
    TF_RND(13) TF_RND(15) TF_RND(26) TF_RND(6)
    x0 += ks1; x1 += ks2 + 1u;
    TF_RND(17) TF_RND(29) TF_RND(16) TF_RND(24)
    x0 += ks2; x1 += ks0 + 2u;
    TF_RND(13) TF_RND(15) TF_RND(26) TF_RND(6)
    x0 += ks0; x1 += ks1 + 3u;
    TF_RND(17) TF_RND(29) TF_RND(16) TF_RND(24)
    x0 += ks1; x1 += ks2 + 4u;
    TF_RND(13) TF_RND(15) TF_RND(26) TF_RND(6)
    x0 += ks2; x1 += ks0 + 5u;
#undef TF_RND
    o0 = x0; o1 = x1;
}

// jax_threefry_partitionable=True (default since jax 0.4.36):
// bits[i] = x0 ^ x1 of threefry2x32(key, (i >> 32, i & 0xffffffff)).
__device__ __forceinline__ int explore_index(int i, int ne) {
    uint32_t o0, o1;
    threefry_key01(0u, (uint32_t)i, o0, o1);
    uint32_t bits = o0 ^ o1;
    float u = __uint_as_float((bits >> 9) | 0x3F800000u) - 1.0f;
    int t = (int)floorf(u * (float)ne);
    return min(t, ne - 1);
}

// ---------- kA: packed top-column partial histograms ----------------------
// One 32-bit word per (nb,u): lo16 = top0 count (H0), hi16 = top1+top2 (H12).
__global__ void k_histA(const int* __restrict__ top,
                        const int* __restrict__ nbid,
                        uint32_t* __restrict__ PA, int n, int chunk) {
    __shared__ uint32_t hist[HH];
    for (int k = threadIdx.x; k < HH; k += blockDim.x) hist[k] = 0u;
    __syncthreads();
    int h = blockIdx.x & 1, s = blockIdx.x >> 1;
    int lo = s * chunk, hi = min(n, lo + chunk);
    const int4* top4 = (const int4*)top;
#define PROC(nb, t0, t1, t2) if (((nb) >> 5) == h) { \
    int r = ((nb) & 31) * N_UNITS; \
    atomicAdd(&hist[r + (t0)], 1u); \
    atomicAdd(&hist[r + (t1)], 0x10000u); \
    atomicAdd(&hist[r + (t2)], 0x10000u); }
    for (int i0 = lo + threadIdx.x * 4; i0 < hi; i0 += blockDim.x * 4) {
        if (i0 + 4 <= hi) {
            int4 nb4 = *(const int4*)(nbid + i0);
            int j = (i0 * 3) >> 2;
            int4 ta = top4[j], tb = top4[j + 1], tc = top4[j + 2];
            PROC(nb4.x, ta.x, ta.y, ta.z)
            PROC(nb4.y, ta.w, tb.x, tb.y)
            PROC(nb4.z, tb.z, tb.w, tc.x)
            PROC(nb4.w, tc.y, tc.z, tc.w)
        } else {
            for (int i = i0; i < hi; ++i)
                PROC(nbid[i], top[3 * i], top[3 * i + 1], top[3 * i + 2])
        }
    }
#undef PROC
    __syncthreads();
    uint32_t* Pb = PA + (size_t)blockIdx.x * HH;
    for (int k = threadIdx.x; k < HH; k += blockDim.x) Pb[k] = hist[k];
}

// ---------- kB: fused reduce + tables + base counts -----------------------
__global__ void k_tables_base(const uint32_t* __restrict__ PA,
                              const int* __restrict__ usn,
                              int* __restrict__ wtbl,
                              int* __restrict__ wne,
                              float* __restrict__ out_counts) {
    __shared__ int scan[512];
    __shared__ int s_c[N_UNITS];
    __shared__ int s_h3[N_UNITS];
    int b = blockIdx.x, u = threadIdx.x;
    int h = b >> 5;
    int base = (b & 31) * N_UNITS;
    int h0 = 0, h12 = 0;
    if (u < N_UNITS) {
#pragma unroll 8
        for (int s = 0; s < NSLICE_A; ++s) {
            uint32_t w = PA[(size_t)(s * 2 + h) * HH + base + u];
            h0  += (int)(w & 0xFFFFu);
            h12 += (int)(w >> 16);
        }
        int h3 = h0 + h12;
        s_h3[u] = h3;
        s_c[u] = h3;              // top0 + top1/top2 contributions
    }
    int p = (u < N_UNITS && h0 > 0) ? 1 : 0;
    scan[u] = p;
    __syncthreads();
    for (int off = 1; off < 512; off <<= 1) {
        int add = (u >= off) ? scan[u - off] : 0;
        __syncthreads();
        scan[u] += add;
        __syncthreads();
    }
    if (p) wtbl[b * N_UNITS + scan[u] - 1] = u;
    if (u == 511) wne[b] = scan[511];
    if (u < N_UNITS) {
        int h3 = s_h3[u];
        if (h3 > 0) {
            int2 nbr = ((const int2*)usn)[u];
            atomicAdd(&s_c[nbr.x], h3);
            atomicAdd(&s_c[nbr.y], h3);
        }
    }
    __syncthreads();
    if (u < N_UNITS)
        out_counts[u * N_NEIGHB + b] = (float)s_c[u];
}

// ---------- k_main: candidates + scores + explore LDS histogram -----------
// Per-256-spike tiles: int4-staged top loads; cand/scores staged in LDS and
// dumped dense with float4 (2.5M store instrs vs 10M strided float2).
__global__ void k_main(const float* __restrict__ logliks,
                       const int* __restrict__ top,
                       const int* __restrict__ usn,
                       const int* __restrict__ nbid,
                       const int* __restrict__ wtbl,
                       const int* __restrict__ wne,
                       uint32_t* __restrict__ PD,
                       float* __restrict__ out_cand,
                       float* __restrict__ out_scores,
                       int n, int chunk) {
    __shared__ uint32_t hist[EH];
    __shared__ int   s_usn[N_UNITS * S];
    __shared__ float s_ll[N_UNITS];
    __shared__ int   s_ne[N_NEIGHB];
    __shared__ int   s_top[BS * 3];
    __shared__ float s_bc[BS * T];
    __shared__ float s_bs[BS * T];
    int tid = threadIdx.x;
    for (int k = tid; k < EH; k += BS) hist[k] = 0u;
    for (int k = tid; k < N_UNITS * S; k += BS) s_usn[k] = usn[k];
    for (int k = tid; k < N_UNITS; k += BS)     s_ll[k]  = logliks[k];
    for (int k = tid; k < N_NEIGHB; k += BS)    s_ne[k]  = wne[k];
    __syncthreads();

    int lo = blockIdx.x * chunk, hi = min(n, lo + chunk);
    for (int t0 = lo; t0 < hi; t0 += BS) {
        int cnt = min(BS, hi - t0);
        // stage this tile's top rows (t0 is 256-aligned -> int4-safe)
        if (cnt == BS) {
            if (tid < (BS * 3) / 4)
                ((int4*)s_top)[tid] = ((const int4*)(top + (size_t)t0 * 3))[tid];
        } else {
            for (int k = tid; k < cnt * 3; k += BS)
                s_top[k] = top[(size_t)t0 * 3 + k];
        }
        __syncthreads();   // also guarantees prior tile's dump is complete

        int i = t0 + tid;
        if (i < hi) {
            int nb = nbid[i];
            int cand[T];
            cand[0] = s_top[tid * 3 + 0];
            cand[1] = s_top[tid * 3 + 1];
            cand[2] = s_top[tid * 3 + 2];
#pragma unroll
            for (int c = 0; c < C; ++c) {
                cand[C + 2 * c]     = s_usn[cand[c] * 2 + 0];
                cand[C + 2 * c + 1] = s_usn[cand[c] * 2 + 1];
            }
            int ne = s_ne[nb];
            if (ne > 0) {
                int t = explore_index(i, ne);
                int ex = wtbl[nb * N_UNITS + t];
                cand[T - 1] = ex;
                // explore tail-count (pre-dup), LDS only
                atomicAdd(&hist[ex * 32 + (nb >> 1)], (nb & 1) ? 0x10000u : 1u);
            } else {
                cand[T - 1] = -1;
            }
#pragma unroll
            for (int jj = 0; jj < T; ++jj) {
                bool dup = false;
#pragma unroll
                for (int k = 0; k < jj; ++k) dup |= (cand[k] == cand[jj]);
                int v = dup ? -1 : cand[jj];   // reference erases dups to -1
                s_bc[tid * T + jj] = (float)v;
                s_bs[tid * T + jj] = (v >= 0) ? s_ll[v] : 0.0f;
            }
        }
        __syncthreads();

        // dense coalesced dump
        int nfloat = cnt * T;
        float* oc = out_cand   + (size_t)t0 * T;
        float* os = out_scores + (size_t)t0 * T;
        int nvec = nfloat & ~3;
        for (int e = tid * 4; e < nvec; e += BS * 4) {
            *(float4*)(oc + e) = *(const float4*)(s_bc + e);
            *(float4*)(os + e) = *(const float4*)(s_bs + e);
        }
        for (int e = nvec + tid; e < nfloat; e += BS) {
            oc[e] = s_bc[e];
            os[e] = s_bs[e];
        }
    }
    __syncthreads();
    uint32_t* Pb = PD + (size_t)blockIdx.x * EH;
    for (int k = tid; k < EH; k += BS) Pb[k] = hist[k];
}

// ---------- kF: parallel reduce explore partials into out_counts ----------
__global__ void k_finalE(const uint32_t* __restrict__ PD,
                         float* __restrict__ out_counts) {
    __shared__ uint32_t red[256];
    int tid = threadIdx.x;
    int wl = tid & 63, g = tid >> 6;            // 4 slice groups
    int w = blockIdx.x * 64 + wl;               // word index in [0, EH)
    uint32_t sum = 0;
#pragma unroll 8
    for (int s = g * (MB / 4); s < (g + 1) * (MB / 4); ++s)
        sum += PD[(size_t)s * EH + w];
    red[tid] = sum;
    __syncthreads();
    if (g == 0) {
        uint32_t tot = red[wl] + red[wl + 64] + red[wl + 128] + red[wl + 192];
        int u = w >> 5, nb2 = (w & 31) * 2;     // packed pair (nb2, nb2+1)
        float2* p = (float2*)(out_counts + u * N_NEIGHB + nb2);
        float2 v = *p;
        v.x += (float)(tot & 0xFFFFu);
        v.y += (float)(tot >> 16);
        *p = v;
    }
}

extern "C" void kernel_launch(void* const* d_in, const int* in_sizes, int n_in,
                              void* d_out, int out_size, void* d_ws, size_t ws_size,
                              hipStream_t stream) {
    const float* logliks = (const float*)d_in[0];
    const int*   top     = (const int*)d_in[1];
    const int*   usn     = (const int*)d_in[2];
    const int*   nbid    = (const int*)d_in[3];

    int n = in_sizes[3];                                 // N_SPIKES
    int chunkA = ((n + NSLICE_A - 1) / NSLICE_A + 3) & ~3;
    int chunkM = (((n + MB - 1) / MB) + BS - 1) & ~(BS - 1);  // 256-aligned

    float* out        = (float*)d_out;
    float* out_cand   = out;
    float* out_counts = out + (size_t)n * T;
    float* out_scores = out_counts + (size_t)N_UNITS * N_NEIGHB;

    // All scratch in d_ws (~39.5 MB used):
    int*      wtbl = (int*)d_ws;                         // [64][400]
    int*      wne  = wtbl + N_NEIGHB * N_UNITS;          // [64]
    uint32_t* PA   = (uint32_t*)(wne + 64);              // 256*12800 = 13.1 MB
    uint32_t* PD   = PA + (size_t)NSLICE_A * 2 * HH;     // 512*12800 = 26.2 MB

    k_histA      <<<NSLICE_A * 2, BS, 0, stream>>>(top, nbid, PA, n, chunkA);
    k_tables_base<<<N_NEIGHB, 512, 0, stream>>>(PA, usn, wtbl, wne, out_counts);
    k_main       <<<MB, BS, 0, stream>>>(logliks, top, usn, nbid, wtbl, wne,
                                         PD, out_cand, out_scores, n, chunkM);
    k_finalE     <<<EH / 64, BS, 0, stream>>>(PD, out_counts);
}